// Round 5
// baseline (303.998 us; speedup 1.0000x reference)
//
#include <hip/hip_runtime.h>
#include <hip/hip_fp16.h>

#define EMB 128

// ---------- fused prep: fp32->fp16 item table + start[] boundaries ----------
__global__ __launch_bounds__(256) void prep_kernel(
    const float* __restrict__ src, __half* __restrict__ dst, int n8,
    const int* __restrict__ beh_user, int* __restrict__ start,
    int n_beh, int n_users)
{
    int t = blockIdx.x * 256 + threadIdx.x;
    if (t < n8) {
        const float4* s = (const float4*)src + (size_t)t * 2;
        float4 f0 = s[0];
        float4 f1 = s[1];
        union { __half h[8]; uint4 u; } pk;
        pk.h[0] = __float2half_rn(f0.x); pk.h[1] = __float2half_rn(f0.y);
        pk.h[2] = __float2half_rn(f0.z); pk.h[3] = __float2half_rn(f0.w);
        pk.h[4] = __float2half_rn(f1.x); pk.h[5] = __float2half_rn(f1.y);
        pk.h[6] = __float2half_rn(f1.z); pk.h[7] = __float2half_rn(f1.w);
        ((uint4*)dst)[t] = pk.u;
    }
    if (t < n_beh) {
        int cur  = beh_user[t];
        int prev = (t == 0) ? -1 : beh_user[t - 1];
        if (cur != prev) {
            for (int u = prev + 1; u <= cur; ++u) start[u] = t;
        }
        if (t == n_beh - 1) {
            for (int u = cur + 1; u <= n_users; ++u) start[u] = n_beh;
        }
    }
}

// Dimension-partitioned gather: grid = 4 dim-blocks x user-blocks.
//   db = blockIdx.x & 3  -> with XCD = blockIdx % 8 round-robin, dim-block db
//   runs only on XCDs {db, db+4}; per-XCD item working set = 25.6/4 = 6.4 MB
//   (vs 4 MiB L2) -> much higher L2 hit rate -> lower average gather latency.
// Each wave: one user, dims [db*32, db*32+32). Row-slice = 64 B = ONE cache
// line. Lanes: octet o = lane>>3 handles behavior slot o; p = lane&7 owns
// dims p*4 (8 B fp16) -> one gather instr fetches EIGHT rows.
// Chunk = 16 behaviors = 2 gathers. 2-deep pipeline as R3 (chunk k+1 in
// flight while consuming chunk k; streams prefetched 2 chunks ahead).
#define ACCUM(W_, c)                                              \
    {                                                             \
        float2 f01 = __half22float2(*(const __half2*)&(W_).x);    \
        float2 f23 = __half22float2(*(const __half2*)&(W_).y);    \
        a0 = fmaf(f01.x, (c), a0); a1 = fmaf(f01.y, (c), a1);     \
        a2 = fmaf(f23.x, (c), a2); a3 = fmaf(f23.y, (c), a3);     \
    }

__global__ __launch_bounds__(256) void per_user_kernel(
    const int*    __restrict__ user_ids,
    const int*    __restrict__ group_ids,
    const int*    __restrict__ beh_item,
    const float*  __restrict__ beh_cnt,
    const float*  __restrict__ user_table,
    const __half* __restrict__ item_f16,
    const int*    __restrict__ start,
    float*        __restrict__ out,
    int n_users)
{
    const int lane = threadIdx.x & 63;
    const int oct  = lane >> 3;    // behavior slot within chunk-half (0..7)
    const int p    = lane & 7;     // owns dims [p*4, p*4+4) of the 32-dim slice
    const int r16  = lane & 15;    // stream-load slot (redundant x4, coalesced)
    const int wave = threadIdx.x >> 6;
    const int db   = blockIdx.x & 3;              // dim-block, pinned to XCD pair
    const int user = (blockIdx.x >> 2) * 4 + wave;

    __shared__ float lds_acc[32];
    __shared__ int   lds_grp[4];
    if (threadIdx.x < 32) lds_acc[threadIdx.x] = 0.0f;

    float a0 = 0.f, a1 = 0.f, a2 = 0.f, a3 = 0.f;
    int g = -1;

    if (user < n_users) {
        const int s = start[user];
        const int e = start[user + 1];
        g = group_ids[user];

        if (s < e) {
            const __half* itp = item_f16 + db * 32 + p * 4; // lane's 8B slice base

            // ---- prologue: stream chunk0 + chunk1, issue chunk0 gathers ----
            int   idx0 = 0; float cnt0 = 0.f;
            {
                int t0 = s + r16;
                if (t0 < e) { idx0 = __builtin_nontemporal_load(beh_item + t0);
                              cnt0 = __builtin_nontemporal_load(beh_cnt + t0); }
            }
            int   idxN = 0; float cntN = 0.f;
            {
                int t1 = s + 16 + r16;
                if (t1 < e) { idxN = __builtin_nontemporal_load(beh_item + t1);
                              cntN = __builtin_nontemporal_load(beh_cnt + t1); }
            }
            int   bi0 = __shfl(idx0, oct,     64);
            int   bi1 = __shfl(idx0, 8 + oct, 64);
            float cc0 = __shfl(cnt0, oct,     64);
            float cc1 = __shfl(cnt0, 8 + oct, 64);
            uint2 wc0 = *(const uint2*)(itp + (size_t)bi0 * EMB);
            uint2 wc1 = *(const uint2*)(itp + (size_t)bi1 * EMB);

            #pragma unroll 2
            for (int j = s; ; ) {
                // (1) stream prefetch chunk k+2 (masked, nontemporal)
                int   idx2 = 0; float cnt2 = 0.f;
                {
                    int t2 = j + 32 + r16;
                    if (t2 < e) { idx2 = __builtin_nontemporal_load(beh_item + t2);
                                  cnt2 = __builtin_nontemporal_load(beh_cnt + t2); }
                }
                // (2) chunk k+1: shfl slots, issue gathers (stay in flight)
                int   ni0 = __shfl(idxN, oct,     64);
                int   ni1 = __shfl(idxN, 8 + oct, 64);
                float nc0 = __shfl(cntN, oct,     64);
                float nc1 = __shfl(cntN, 8 + oct, 64);
                uint2 wn0 = *(const uint2*)(itp + (size_t)ni0 * EMB);
                uint2 wn1 = *(const uint2*)(itp + (size_t)ni1 * EMB);

                // (3) consume chunk k
                ACCUM(wc0, cc0);
                ACCUM(wc1, cc1);

                j += 16;
                if (j >= e) break;

                // (4) rotate roles
                wc0 = wn0; wc1 = wn1;
                cc0 = nc0; cc1 = nc1;
                idxN = idx2; cntN = cnt2;
            }
        }

        // reduce across the 8 octets (lanes with equal p hold same dims)
        a0 += __shfl_xor(a0,  8, 64); a1 += __shfl_xor(a1,  8, 64);
        a2 += __shfl_xor(a2,  8, 64); a3 += __shfl_xor(a3,  8, 64);
        a0 += __shfl_xor(a0, 16, 64); a1 += __shfl_xor(a1, 16, 64);
        a2 += __shfl_xor(a2, 16, 64); a3 += __shfl_xor(a3, 16, 64);
        a0 += __shfl_xor(a0, 32, 64); a1 += __shfl_xor(a1, 32, 64);
        a2 += __shfl_xor(a2, 32, 64); a3 += __shfl_xor(a3, 32, 64);

        const int uid = user_ids[user];
        if (uid != 0) {
            float4 ue = *(const float4*)(user_table + (size_t)uid * EMB + db * 32 + p * 4);
            a0 *= ue.x; a1 *= ue.y; a2 *= ue.z; a3 *= ue.w;
        } else {
            a0 = a1 = a2 = a3 = 0.f;
        }
    }

    if (lane == 0) lds_grp[wave] = g;
    __syncthreads();

    const int g0 = lds_grp[0];
    const bool same = (g0 >= 0) && (lds_grp[1] == g0) &&
                      (lds_grp[2] == g0) && (lds_grp[3] == g0);
    if (same) {
        if (oct == 0) {   // 8 lanes x 4 dims per wave
            atomicAdd(&lds_acc[p * 4 + 0], a0);
            atomicAdd(&lds_acc[p * 4 + 1], a1);
            atomicAdd(&lds_acc[p * 4 + 2], a2);
            atomicAdd(&lds_acc[p * 4 + 3], a3);
        }
        __syncthreads();
        if (threadIdx.x < 32) {
            atomicAdd(&out[(size_t)g0 * EMB + db * 32 + threadIdx.x],
                      lds_acc[threadIdx.x]);
        }
    } else if (g >= 0 && oct == 0) {
        atomicAdd(&out[(size_t)g * EMB + db * 32 + p * 4 + 0], a0);
        atomicAdd(&out[(size_t)g * EMB + db * 32 + p * 4 + 1], a1);
        atomicAdd(&out[(size_t)g * EMB + db * 32 + p * 4 + 2], a2);
        atomicAdd(&out[(size_t)g * EMB + db * 32 + p * 4 + 3], a3);
    }
}

// ---------- fp32 fallback (ws too small for fp16 table) ----------
__global__ __launch_bounds__(256) void per_user_f32_kernel(
    const int*   __restrict__ user_ids,
    const int*   __restrict__ group_ids,
    const int*   __restrict__ beh_item,
    const float* __restrict__ beh_cnt,
    const int*   __restrict__ beh_user,
    const float* __restrict__ user_table,
    const float* __restrict__ item_f32,
    float*       __restrict__ out,
    int n_users, int n_beh)
{
    const int lane = threadIdx.x & 63;
    const int wave = threadIdx.x >> 6;
    const int user = blockIdx.x * 4 + wave;
    float2 acc = make_float2(0.f, 0.f);
    int g = -1;
    if (user < n_users) {
        int lo = 0, hi = n_beh;
        while (lo < hi) { int m = (lo + hi) >> 1; if (beh_user[m] < user) lo = m + 1; else hi = m; }
        int s = lo; hi = n_beh;
        while (lo < hi) { int m = (lo + hi) >> 1; if (beh_user[m] <= user) lo = m + 1; else hi = m; }
        int e = lo;
        for (int j = s; j < e; ++j) {
            int   b = beh_item[j];
            float c = beh_cnt[j];
            float2 v = *(const float2*)(item_f32 + (size_t)b * EMB + lane * 2);
            acc.x = fmaf(v.x, c, acc.x);
            acc.y = fmaf(v.y, c, acc.y);
        }
        int uid = user_ids[user];
        float2 ue = make_float2(0.f, 0.f);
        if (uid != 0) ue = *(const float2*)(user_table + (size_t)uid * EMB + lane * 2);
        acc.x *= ue.x; acc.y *= ue.y;
        g = group_ids[user];
    }
    if (g >= 0) {
        atomicAdd(&out[(size_t)g * EMB + lane * 2],     acc.x);
        atomicAdd(&out[(size_t)g * EMB + lane * 2 + 1], acc.y);
    }
}

extern "C" void kernel_launch(void* const* d_in, const int* in_sizes, int n_in,
                              void* d_out, int out_size, void* d_ws, size_t ws_size,
                              hipStream_t stream) {
    const int*   user_ids   = (const int*)  d_in[0];
    const int*   group_ids  = (const int*)  d_in[1];
    const int*   beh_item   = (const int*)  d_in[2];
    const float* beh_cnt    = (const float*)d_in[3];
    const int*   beh_user   = (const int*)  d_in[4];
    const float* user_table = (const float*)d_in[5];
    const float* item_table = (const float*)d_in[6];

    const int n_users = in_sizes[0];
    const int n_beh   = in_sizes[2];
    const int item_n  = in_sizes[6] / EMB;

    float* out = (float*)d_out;
    (void)hipMemsetAsync(out, 0, (size_t)out_size * sizeof(float), stream);

    // ws layout: start | item_f16 (256B aligned)
    size_t start_bytes = (size_t)(n_users + 1) * sizeof(int);
    size_t f16_off     = (start_bytes + 255) & ~(size_t)255;
    size_t f16_bytes   = (size_t)item_n * EMB * sizeof(__half);

    if (ws_size < f16_off + f16_bytes) {
        int ublocks = (n_users + 3) / 4;
        per_user_f32_kernel<<<ublocks, 256, 0, stream>>>(
            user_ids, group_ids, beh_item, beh_cnt, beh_user,
            user_table, item_table, out, n_users, n_beh);
        return;
    }

    int*    start    = (int*)d_ws;
    __half* item_f16 = (__half*)((char*)d_ws + f16_off);

    int n8 = (item_n * EMB) / 8;
    int prep_n = n8 > n_beh ? n8 : n_beh;
    prep_kernel<<<(prep_n + 255) / 256, 256, 0, stream>>>(
        item_table, item_f16, n8, beh_user, start, n_beh, n_users);

    // grid: 4 dim-blocks (low 2 bits -> XCD pinning) x user-blocks
    int ublocks = (n_users + 3) / 4;
    per_user_kernel<<<ublocks * 4, 256, 0, stream>>>(
        user_ids, group_ids, beh_item, beh_cnt,
        user_table, item_f16, start, out, n_users);
}

// Round 6
// 228.324 us; speedup vs baseline: 1.3314x; 1.3314x over previous
//
#include <hip/hip_runtime.h>
#include <hip/hip_fp16.h>

#define EMB 128

// ---------- fused prep: fp32->fp16 item table + start[] boundaries ----------
__global__ __launch_bounds__(256) void prep_kernel(
    const float* __restrict__ src, __half* __restrict__ dst, int n8,
    const int* __restrict__ beh_user, int* __restrict__ start,
    int n_beh, int n_users)
{
    int t = blockIdx.x * 256 + threadIdx.x;
    if (t < n8) {
        const float4* s = (const float4*)src + (size_t)t * 2;
        float4 f0 = s[0];
        float4 f1 = s[1];
        union { __half h[8]; uint4 u; } pk;
        pk.h[0] = __float2half_rn(f0.x); pk.h[1] = __float2half_rn(f0.y);
        pk.h[2] = __float2half_rn(f0.z); pk.h[3] = __float2half_rn(f0.w);
        pk.h[4] = __float2half_rn(f1.x); pk.h[5] = __float2half_rn(f1.y);
        pk.h[6] = __float2half_rn(f1.z); pk.h[7] = __float2half_rn(f1.w);
        ((uint4*)dst)[t] = pk.u;
    }
    if (t < n_beh) {
        int cur  = beh_user[t];
        int prev = (t == 0) ? -1 : beh_user[t - 1];
        if (cur != prev) {
            for (int u = prev + 1; u <= cur; ++u) start[u] = t;
        }
        if (t == n_beh - 1) {
            for (int u = cur + 1; u <= n_users; ++u) start[u] = n_beh;
        }
    }
}

// One wave per user. Quarter-wave rows: 16 lanes per row, each lane owns
// 8 dims (16 B fp16, dwordx4) -> one gather instr fetches FOUR rows (16 lines).
// 3-deep software pipeline (R3 was 2-deep; achieved fetch-BW rose 2.57->2.83
// TB/s going 1->2, this probes whether outstanding-lines per wave still bind):
//   invariant at loop top: gathers for chunks k (wa*) and k+1 (wb*) ISSUED,
//   stream for chunk k+2 in regs (idxC/cntC).
//   body: (1) stream-prefetch chunk k+3  (2) shfl chunk k+2 slots + issue its
//   gathers  (3) ACCUM chunk k (vmcnt waits only k's 4 loads; 8 newer stay in
//   flight)  (4) rotate.
// User-row load hoisted to prologue (overlaps the whole gather loop).
#define ACCUM(W_, c)                                              \
    {                                                             \
        float2 f01 = __half22float2(*(const __half2*)&(W_).x);    \
        float2 f23 = __half22float2(*(const __half2*)&(W_).y);    \
        float2 f45 = __half22float2(*(const __half2*)&(W_).z);    \
        float2 f67 = __half22float2(*(const __half2*)&(W_).w);    \
        a0 = fmaf(f01.x, (c), a0); a1 = fmaf(f01.y, (c), a1);     \
        a2 = fmaf(f23.x, (c), a2); a3 = fmaf(f23.y, (c), a3);     \
        a4 = fmaf(f45.x, (c), a4); a5 = fmaf(f45.y, (c), a5);     \
        a6 = fmaf(f67.x, (c), a6); a7 = fmaf(f67.y, (c), a7);     \
    }

#define SHFL4(DI_, DC_, SI_, SC_)                                 \
    DI_##0 = __shfl(SI_, q * 4 + 0, 16);                          \
    DI_##1 = __shfl(SI_, q * 4 + 1, 16);                          \
    DI_##2 = __shfl(SI_, q * 4 + 2, 16);                          \
    DI_##3 = __shfl(SI_, q * 4 + 3, 16);                          \
    DC_##0 = __shfl(SC_, q * 4 + 0, 16);                          \
    DC_##1 = __shfl(SC_, q * 4 + 1, 16);                          \
    DC_##2 = __shfl(SC_, q * 4 + 2, 16);                          \
    DC_##3 = __shfl(SC_, q * 4 + 3, 16);

__global__ __launch_bounds__(256) void per_user_kernel(
    const int*    __restrict__ user_ids,
    const int*    __restrict__ group_ids,
    const int*    __restrict__ beh_item,
    const float*  __restrict__ beh_cnt,
    const float*  __restrict__ user_table,
    const __half* __restrict__ item_f16,
    const int*    __restrict__ start,
    float*        __restrict__ out,
    int n_users)
{
    const int lane = threadIdx.x & 63;
    const int q    = lane >> 4;   // quarter 0..3
    const int r    = lane & 15;   // lane within quarter; owns dims [r*8, r*8+8)
    const int wave = threadIdx.x >> 6;
    const int user = blockIdx.x * 4 + wave;

    __shared__ float lds_acc[EMB];
    __shared__ int   lds_grp[4];
    if (threadIdx.x < EMB) lds_acc[threadIdx.x] = 0.0f;

    float a0 = 0.f, a1 = 0.f, a2 = 0.f, a3 = 0.f;
    float a4 = 0.f, a5 = 0.f, a6 = 0.f, a7 = 0.f;
    int g = -1;

    if (user < n_users) {
        const int s = start[user];
        const int e = start[user + 1];
        g = group_ids[user];

        // hoisted: user row load overlaps the whole gather loop
        const int uid = user_ids[user];
        float4 u0 = make_float4(0.f, 0.f, 0.f, 0.f);
        float4 u1 = u0;
        if (uid != 0) {
            const float* up = user_table + (size_t)uid * EMB + r * 8;
            u0 = *(const float4*)up;
            u1 = *(const float4*)(up + 4);
        }

        if (s < e) {
            const __half* itp = item_f16 + r * 8;  // this lane's 16B slice base

            // ---- prologue: streams for chunks 0,1,2; gathers for 0,1 ----
            int idxA = 0; float cntA = 0.f;
            { int t0 = s + r;
              if (t0 < e) { idxA = __builtin_nontemporal_load(beh_item + t0);
                            cntA = __builtin_nontemporal_load(beh_cnt + t0); } }
            int idxB = 0; float cntB = 0.f;
            { int t1 = s + 16 + r;
              if (t1 < e) { idxB = __builtin_nontemporal_load(beh_item + t1);
                            cntB = __builtin_nontemporal_load(beh_cnt + t1); } }
            int idxC = 0; float cntC = 0.f;
            { int t2 = s + 32 + r;
              if (t2 < e) { idxC = __builtin_nontemporal_load(beh_item + t2);
                            cntC = __builtin_nontemporal_load(beh_cnt + t2); } }

            int aI0, aI1, aI2, aI3; float aC0, aC1, aC2, aC3;
            SHFL4(aI, aC, idxA, cntA);
            uint4 wa0 = *(const uint4*)(itp + (size_t)aI0 * EMB);
            uint4 wa1 = *(const uint4*)(itp + (size_t)aI1 * EMB);
            uint4 wa2 = *(const uint4*)(itp + (size_t)aI2 * EMB);
            uint4 wa3 = *(const uint4*)(itp + (size_t)aI3 * EMB);

            int bI0, bI1, bI2, bI3; float bC0, bC1, bC2, bC3;
            SHFL4(bI, bC, idxB, cntB);
            uint4 wb0 = *(const uint4*)(itp + (size_t)bI0 * EMB);
            uint4 wb1 = *(const uint4*)(itp + (size_t)bI1 * EMB);
            uint4 wb2 = *(const uint4*)(itp + (size_t)bI2 * EMB);
            uint4 wb3 = *(const uint4*)(itp + (size_t)bI3 * EMB);

            for (int j = s; ; ) {
                // (1) stream prefetch chunk k+3 (masked, nontemporal)
                int idxD = 0; float cntD = 0.f;
                { int t3 = j + 48 + r;
                  if (t3 < e) { idxD = __builtin_nontemporal_load(beh_item + t3);
                                cntD = __builtin_nontemporal_load(beh_cnt + t3); } }

                // (2) chunk k+2: shfl slots, issue gathers (stay in flight)
                int cI0, cI1, cI2, cI3; float cC0, cC1, cC2, cC3;
                SHFL4(cI, cC, idxC, cntC);
                uint4 wc0 = *(const uint4*)(itp + (size_t)cI0 * EMB);
                uint4 wc1 = *(const uint4*)(itp + (size_t)cI1 * EMB);
                uint4 wc2 = *(const uint4*)(itp + (size_t)cI2 * EMB);
                uint4 wc3 = *(const uint4*)(itp + (size_t)cI3 * EMB);

                // (3) consume chunk k
                ACCUM(wa0, aC0);
                ACCUM(wa1, aC1);
                ACCUM(wa2, aC2);
                ACCUM(wa3, aC3);

                j += 16;
                if (j >= e) break;

                // (4) rotate roles: A<-B, B<-C(issued), C-stream<-D
                wa0 = wb0; wa1 = wb1; wa2 = wb2; wa3 = wb3;
                aC0 = bC0; aC1 = bC1; aC2 = bC2; aC3 = bC3;
                wb0 = wc0; wb1 = wc1; wb2 = wc2; wb3 = wc3;
                bC0 = cC0; bC1 = cC1; bC2 = cC2; bC3 = cC3;
                idxC = idxD; cntC = cntD;
            }
        }

        // combine the 4 quarters (lanes with equal r hold partials of same dims)
        a0 += __shfl_xor(a0, 16, 64); a1 += __shfl_xor(a1, 16, 64);
        a2 += __shfl_xor(a2, 16, 64); a3 += __shfl_xor(a3, 16, 64);
        a4 += __shfl_xor(a4, 16, 64); a5 += __shfl_xor(a5, 16, 64);
        a6 += __shfl_xor(a6, 16, 64); a7 += __shfl_xor(a7, 16, 64);
        a0 += __shfl_xor(a0, 32, 64); a1 += __shfl_xor(a1, 32, 64);
        a2 += __shfl_xor(a2, 32, 64); a3 += __shfl_xor(a3, 32, 64);
        a4 += __shfl_xor(a4, 32, 64); a5 += __shfl_xor(a5, 32, 64);
        a6 += __shfl_xor(a6, 32, 64); a7 += __shfl_xor(a7, 32, 64);

        a0 *= u0.x; a1 *= u0.y; a2 *= u0.z; a3 *= u0.w;
        a4 *= u1.x; a5 *= u1.y; a6 *= u1.z; a7 *= u1.w;
    }

    // quarter q writes dims r*8 + 2q, r*8 + 2q + 1 (union over q,r = 128 dims)
    float v0, v1;
    if      (q == 0) { v0 = a0; v1 = a1; }
    else if (q == 1) { v0 = a2; v1 = a3; }
    else if (q == 2) { v0 = a4; v1 = a5; }
    else             { v0 = a6; v1 = a7; }
    const int d0 = r * 8 + q * 2;

    if (lane == 0) lds_grp[wave] = g;
    __syncthreads();

    const int g0 = lds_grp[0];
    const bool same = (g0 >= 0) && (lds_grp[1] == g0) &&
                      (lds_grp[2] == g0) && (lds_grp[3] == g0);
    if (same) {
        atomicAdd(&lds_acc[d0],     v0);
        atomicAdd(&lds_acc[d0 + 1], v1);
        __syncthreads();
        if (threadIdx.x < 64) {
            const int d = threadIdx.x * 2;
            atomicAdd(&out[(size_t)g0 * EMB + d],     lds_acc[d]);
            atomicAdd(&out[(size_t)g0 * EMB + d + 1], lds_acc[d + 1]);
        }
    } else if (g >= 0) {
        atomicAdd(&out[(size_t)g * EMB + d0],     v0);
        atomicAdd(&out[(size_t)g * EMB + d0 + 1], v1);
    }
}

// ---------- fp32 fallback (ws too small for fp16 table) ----------
__global__ __launch_bounds__(256) void per_user_f32_kernel(
    const int*   __restrict__ user_ids,
    const int*   __restrict__ group_ids,
    const int*   __restrict__ beh_item,
    const float* __restrict__ beh_cnt,
    const int*   __restrict__ beh_user,
    const float* __restrict__ user_table,
    const float* __restrict__ item_f32,
    float*       __restrict__ out,
    int n_users, int n_beh)
{
    const int lane = threadIdx.x & 63;
    const int wave = threadIdx.x >> 6;
    const int user = blockIdx.x * 4 + wave;
    float2 acc = make_float2(0.f, 0.f);
    int g = -1;
    if (user < n_users) {
        int lo = 0, hi = n_beh;
        while (lo < hi) { int m = (lo + hi) >> 1; if (beh_user[m] < user) lo = m + 1; else hi = m; }
        int s = lo; hi = n_beh;
        while (lo < hi) { int m = (lo + hi) >> 1; if (beh_user[m] <= user) lo = m + 1; else hi = m; }
        int e = lo;
        for (int j = s; j < e; ++j) {
            int   b = beh_item[j];
            float c = beh_cnt[j];
            float2 v = *(const float2*)(item_f32 + (size_t)b * EMB + lane * 2);
            acc.x = fmaf(v.x, c, acc.x);
            acc.y = fmaf(v.y, c, acc.y);
        }
        int uid = user_ids[user];
        float2 ue = make_float2(0.f, 0.f);
        if (uid != 0) ue = *(const float2*)(user_table + (size_t)uid * EMB + lane * 2);
        acc.x *= ue.x; acc.y *= ue.y;
        g = group_ids[user];
    }
    if (g >= 0) {
        atomicAdd(&out[(size_t)g * EMB + lane * 2],     acc.x);
        atomicAdd(&out[(size_t)g * EMB + lane * 2 + 1], acc.y);
    }
}

extern "C" void kernel_launch(void* const* d_in, const int* in_sizes, int n_in,
                              void* d_out, int out_size, void* d_ws, size_t ws_size,
                              hipStream_t stream) {
    const int*   user_ids   = (const int*)  d_in[0];
    const int*   group_ids  = (const int*)  d_in[1];
    const int*   beh_item   = (const int*)  d_in[2];
    const float* beh_cnt    = (const float*)d_in[3];
    const int*   beh_user   = (const int*)  d_in[4];
    const float* user_table = (const float*)d_in[5];
    const float* item_table = (const float*)d_in[6];

    const int n_users = in_sizes[0];
    const int n_beh   = in_sizes[2];
    const int item_n  = in_sizes[6] / EMB;

    float* out = (float*)d_out;
    (void)hipMemsetAsync(out, 0, (size_t)out_size * sizeof(float), stream);

    // ws layout: start | item_f16 (256B aligned)
    size_t start_bytes = (size_t)(n_users + 1) * sizeof(int);
    size_t f16_off     = (start_bytes + 255) & ~(size_t)255;
    size_t f16_bytes   = (size_t)item_n * EMB * sizeof(__half);

    if (ws_size < f16_off + f16_bytes) {
        int ublocks = (n_users + 3) / 4;
        per_user_f32_kernel<<<ublocks, 256, 0, stream>>>(
            user_ids, group_ids, beh_item, beh_cnt, beh_user,
            user_table, item_table, out, n_users, n_beh);
        return;
    }

    int*    start    = (int*)d_ws;
    __half* item_f16 = (__half*)((char*)d_ws + f16_off);

    int n8 = (item_n * EMB) / 8;
    int prep_n = n8 > n_beh ? n8 : n_beh;
    prep_kernel<<<(prep_n + 255) / 256, 256, 0, stream>>>(
        item_table, item_f16, n8, beh_user, start, n_beh, n_users);

    int ublocks = (n_users + 3) / 4;
    per_user_kernel<<<ublocks, 256, 0, stream>>>(
        user_ids, group_ids, beh_item, beh_cnt,
        user_table, item_f16, start, out, n_users);
}

// Round 7
// 225.093 us; speedup vs baseline: 1.3505x; 1.0144x over previous
//
#include <hip/hip_runtime.h>
#include <hip/hip_fp16.h>

#define EMB 128

// ---------- fused prep: fp32->fp16 item table + start[] boundaries ----------
__global__ __launch_bounds__(256) void prep_kernel(
    const float* __restrict__ src, __half* __restrict__ dst, int n8,
    const int* __restrict__ beh_user, int* __restrict__ start,
    int n_beh, int n_users)
{
    int t = blockIdx.x * 256 + threadIdx.x;
    if (t < n8) {
        const float4* s = (const float4*)src + (size_t)t * 2;
        float4 f0 = s[0];
        float4 f1 = s[1];
        union { __half h[8]; uint4 u; } pk;
        pk.h[0] = __float2half_rn(f0.x); pk.h[1] = __float2half_rn(f0.y);
        pk.h[2] = __float2half_rn(f0.z); pk.h[3] = __float2half_rn(f0.w);
        pk.h[4] = __float2half_rn(f1.x); pk.h[5] = __float2half_rn(f1.y);
        pk.h[6] = __float2half_rn(f1.z); pk.h[7] = __float2half_rn(f1.w);
        ((uint4*)dst)[t] = pk.u;
    }
    if (t < n_beh) {
        int cur  = beh_user[t];
        int prev = (t == 0) ? -1 : beh_user[t - 1];
        if (cur != prev) {
            for (int u = prev + 1; u <= cur; ++u) start[u] = t;
        }
        if (t == n_beh - 1) {
            for (int u = cur + 1; u <= n_users; ++u) start[u] = n_beh;
        }
    }
}

// One wave per user. Quarter-wave row layout: 16 lanes per row, each lane owns
// 8 dims (16 B fp16, dwordx4) -> one gather instr fetches FOUR rows.
//
// 2-deep software pipeline — measured optimum (R3=90.1µs; 1-deep=99µs,
// 3-deep=97µs R6; 12-bit rows=97µs R4; dim-partition=176µs R5):
//   invariant at loop top: gathers for chunk k ISSUED (wc*), stream for
//   chunk k+1 in regs (idxN/cntN), counts for chunk k in regs (cc*).
//   body: (1) stream-prefetch chunk k+2  (2) shfl chunk k+1 slots + issue
//   its 4 gathers  (3) ACCUM chunk k (partial vmcnt wait; k+1 stays in
//   flight)  (4) rotate.
// Perf model (verified across 6 variants): dur ≈ FETCH_SIZE / 2.8 TB/s;
// FETCH ≈ 255 MB is the irreducible L2-miss floor for a 25.6 MB table
// gathered uniformly against 4 MiB/XCD L2.
// NOTE: macro parameter must NOT be named `w` (preprocessor would rewrite
// the `.w` member access).
#define ACCUM(W_, c)                                              \
    {                                                             \
        float2 f01 = __half22float2(*(const __half2*)&(W_).x);    \
        float2 f23 = __half22float2(*(const __half2*)&(W_).y);    \
        float2 f45 = __half22float2(*(const __half2*)&(W_).z);    \
        float2 f67 = __half22float2(*(const __half2*)&(W_).w);    \
        a0 = fmaf(f01.x, (c), a0); a1 = fmaf(f01.y, (c), a1);     \
        a2 = fmaf(f23.x, (c), a2); a3 = fmaf(f23.y, (c), a3);     \
        a4 = fmaf(f45.x, (c), a4); a5 = fmaf(f45.y, (c), a5);     \
        a6 = fmaf(f67.x, (c), a6); a7 = fmaf(f67.y, (c), a7);     \
    }

__global__ __launch_bounds__(256) void per_user_kernel(
    const int*    __restrict__ user_ids,
    const int*    __restrict__ group_ids,
    const int*    __restrict__ beh_item,
    const float*  __restrict__ beh_cnt,
    const float*  __restrict__ user_table,
    const __half* __restrict__ item_f16,
    const int*    __restrict__ start,
    float*        __restrict__ out,
    int n_users)
{
    const int lane = threadIdx.x & 63;
    const int q    = lane >> 4;   // quarter 0..3
    const int r    = lane & 15;   // lane within quarter; owns dims [r*8, r*8+8)
    const int wave = threadIdx.x >> 6;
    const int user = blockIdx.x * 4 + wave;

    __shared__ float lds_acc[EMB];
    __shared__ int   lds_grp[4];
    if (threadIdx.x < EMB) lds_acc[threadIdx.x] = 0.0f;

    float a0 = 0.f, a1 = 0.f, a2 = 0.f, a3 = 0.f;
    float a4 = 0.f, a5 = 0.f, a6 = 0.f, a7 = 0.f;
    int g = -1;

    if (user < n_users) {
        const int s = start[user];
        const int e = start[user + 1];
        g = group_ids[user];

        if (s < e) {
            const __half* itp = item_f16 + r * 8;  // this lane's 16B slice of any row

            // ---- prologue: stream chunk0 + chunk1, issue chunk0 gathers ----
            int   idx0 = 0; float cnt0 = 0.f;
            {
                int t0 = s + r;
                if (t0 < e) { idx0 = __builtin_nontemporal_load(beh_item + t0);
                              cnt0 = __builtin_nontemporal_load(beh_cnt + t0); }
            }
            int   idxN = 0; float cntN = 0.f;
            {
                int t1 = s + 16 + r;
                if (t1 < e) { idxN = __builtin_nontemporal_load(beh_item + t1);
                              cntN = __builtin_nontemporal_load(beh_cnt + t1); }
            }
            int   bi0 = __shfl(idx0, q * 4 + 0, 16);
            int   bi1 = __shfl(idx0, q * 4 + 1, 16);
            int   bi2 = __shfl(idx0, q * 4 + 2, 16);
            int   bi3 = __shfl(idx0, q * 4 + 3, 16);
            float cc0 = __shfl(cnt0, q * 4 + 0, 16);
            float cc1 = __shfl(cnt0, q * 4 + 1, 16);
            float cc2 = __shfl(cnt0, q * 4 + 2, 16);
            float cc3 = __shfl(cnt0, q * 4 + 3, 16);
            uint4 wc0 = *(const uint4*)(itp + (size_t)bi0 * EMB);
            uint4 wc1 = *(const uint4*)(itp + (size_t)bi1 * EMB);
            uint4 wc2 = *(const uint4*)(itp + (size_t)bi2 * EMB);
            uint4 wc3 = *(const uint4*)(itp + (size_t)bi3 * EMB);

            #pragma unroll 2
            for (int j = s; ; ) {
                // (1) stream prefetch chunk k+2 (masked, nontemporal)
                int   idx2 = 0; float cnt2 = 0.f;
                {
                    int t2 = j + 32 + r;
                    if (t2 < e) { idx2 = __builtin_nontemporal_load(beh_item + t2);
                                  cnt2 = __builtin_nontemporal_load(beh_cnt + t2); }
                }
                // (2) chunk k+1: shfl slots, issue its gathers (stay in flight)
                int   ni0 = __shfl(idxN, q * 4 + 0, 16);
                int   ni1 = __shfl(idxN, q * 4 + 1, 16);
                int   ni2 = __shfl(idxN, q * 4 + 2, 16);
                int   ni3 = __shfl(idxN, q * 4 + 3, 16);
                float nc0 = __shfl(cntN, q * 4 + 0, 16);
                float nc1 = __shfl(cntN, q * 4 + 1, 16);
                float nc2 = __shfl(cntN, q * 4 + 2, 16);
                float nc3 = __shfl(cntN, q * 4 + 3, 16);
                uint4 wn0 = *(const uint4*)(itp + (size_t)ni0 * EMB);
                uint4 wn1 = *(const uint4*)(itp + (size_t)ni1 * EMB);
                uint4 wn2 = *(const uint4*)(itp + (size_t)ni2 * EMB);
                uint4 wn3 = *(const uint4*)(itp + (size_t)ni3 * EMB);

                // (3) consume chunk k
                ACCUM(wc0, cc0);
                ACCUM(wc1, cc1);
                ACCUM(wc2, cc2);
                ACCUM(wc3, cc3);

                j += 16;
                if (j >= e) break;

                // (4) rotate roles
                wc0 = wn0; wc1 = wn1; wc2 = wn2; wc3 = wn3;
                cc0 = nc0; cc1 = nc1; cc2 = nc2; cc3 = nc3;
                idxN = idx2; cntN = cnt2;
            }
        }

        // combine the 4 quarters (lanes with equal r hold partials of same dims)
        a0 += __shfl_xor(a0, 16, 64); a1 += __shfl_xor(a1, 16, 64);
        a2 += __shfl_xor(a2, 16, 64); a3 += __shfl_xor(a3, 16, 64);
        a4 += __shfl_xor(a4, 16, 64); a5 += __shfl_xor(a5, 16, 64);
        a6 += __shfl_xor(a6, 16, 64); a7 += __shfl_xor(a7, 16, 64);
        a0 += __shfl_xor(a0, 32, 64); a1 += __shfl_xor(a1, 32, 64);
        a2 += __shfl_xor(a2, 32, 64); a3 += __shfl_xor(a3, 32, 64);
        a4 += __shfl_xor(a4, 32, 64); a5 += __shfl_xor(a5, 32, 64);
        a6 += __shfl_xor(a6, 32, 64); a7 += __shfl_xor(a7, 32, 64);

        const int uid = user_ids[user];
        if (uid != 0) {
            // once-use row: nontemporal scalar loads (same cache lines, no L2 alloc)
            const float* up = user_table + (size_t)uid * EMB + r * 8;
            a0 *= __builtin_nontemporal_load(up + 0);
            a1 *= __builtin_nontemporal_load(up + 1);
            a2 *= __builtin_nontemporal_load(up + 2);
            a3 *= __builtin_nontemporal_load(up + 3);
            a4 *= __builtin_nontemporal_load(up + 4);
            a5 *= __builtin_nontemporal_load(up + 5);
            a6 *= __builtin_nontemporal_load(up + 6);
            a7 *= __builtin_nontemporal_load(up + 7);
        } else {
            a0 = a1 = a2 = a3 = a4 = a5 = a6 = a7 = 0.f;
        }
    }

    // quarter q writes dims r*8 + 2q, r*8 + 2q + 1 (union over q,r = 128 dims)
    float v0, v1;
    if      (q == 0) { v0 = a0; v1 = a1; }
    else if (q == 1) { v0 = a2; v1 = a3; }
    else if (q == 2) { v0 = a4; v1 = a5; }
    else             { v0 = a6; v1 = a7; }
    const int d0 = r * 8 + q * 2;

    if (lane == 0) lds_grp[wave] = g;
    __syncthreads();

    const int g0 = lds_grp[0];
    const bool same = (g0 >= 0) && (lds_grp[1] == g0) &&
                      (lds_grp[2] == g0) && (lds_grp[3] == g0);
    if (same) {
        atomicAdd(&lds_acc[d0],     v0);
        atomicAdd(&lds_acc[d0 + 1], v1);
        __syncthreads();
        if (threadIdx.x < 64) {
            const int d = threadIdx.x * 2;
            atomicAdd(&out[(size_t)g0 * EMB + d],     lds_acc[d]);
            atomicAdd(&out[(size_t)g0 * EMB + d + 1], lds_acc[d + 1]);
        }
    } else if (g >= 0) {
        atomicAdd(&out[(size_t)g * EMB + d0],     v0);
        atomicAdd(&out[(size_t)g * EMB + d0 + 1], v1);
    }
}

// ---------- fp32 fallback (ws too small for fp16 table) ----------
__global__ __launch_bounds__(256) void per_user_f32_kernel(
    const int*   __restrict__ user_ids,
    const int*   __restrict__ group_ids,
    const int*   __restrict__ beh_item,
    const float* __restrict__ beh_cnt,
    const int*   __restrict__ beh_user,
    const float* __restrict__ user_table,
    const float* __restrict__ item_f32,
    float*       __restrict__ out,
    int n_users, int n_beh)
{
    const int lane = threadIdx.x & 63;
    const int wave = threadIdx.x >> 6;
    const int user = blockIdx.x * 4 + wave;
    float2 acc = make_float2(0.f, 0.f);
    int g = -1;
    if (user < n_users) {
        int lo = 0, hi = n_beh;
        while (lo < hi) { int m = (lo + hi) >> 1; if (beh_user[m] < user) lo = m + 1; else hi = m; }
        int s = lo; hi = n_beh;
        while (lo < hi) { int m = (lo + hi) >> 1; if (beh_user[m] <= user) lo = m + 1; else hi = m; }
        int e = lo;
        for (int j = s; j < e; ++j) {
            int   b = beh_item[j];
            float c = beh_cnt[j];
            float2 v = *(const float2*)(item_f32 + (size_t)b * EMB + lane * 2);
            acc.x = fmaf(v.x, c, acc.x);
            acc.y = fmaf(v.y, c, acc.y);
        }
        int uid = user_ids[user];
        float2 ue = make_float2(0.f, 0.f);
        if (uid != 0) ue = *(const float2*)(user_table + (size_t)uid * EMB + lane * 2);
        acc.x *= ue.x; acc.y *= ue.y;
        g = group_ids[user];
    }
    if (g >= 0) {
        atomicAdd(&out[(size_t)g * EMB + lane * 2],     acc.x);
        atomicAdd(&out[(size_t)g * EMB + lane * 2 + 1], acc.y);
    }
}

extern "C" void kernel_launch(void* const* d_in, const int* in_sizes, int n_in,
                              void* d_out, int out_size, void* d_ws, size_t ws_size,
                              hipStream_t stream) {
    const int*   user_ids   = (const int*)  d_in[0];
    const int*   group_ids  = (const int*)  d_in[1];
    const int*   beh_item   = (const int*)  d_in[2];
    const float* beh_cnt    = (const float*)d_in[3];
    const int*   beh_user   = (const int*)  d_in[4];
    const float* user_table = (const float*)d_in[5];
    const float* item_table = (const float*)d_in[6];

    const int n_users = in_sizes[0];
    const int n_beh   = in_sizes[2];
    const int item_n  = in_sizes[6] / EMB;

    float* out = (float*)d_out;
    (void)hipMemsetAsync(out, 0, (size_t)out_size * sizeof(float), stream);

    // ws layout: start | item_f16 (256B aligned)
    size_t start_bytes = (size_t)(n_users + 1) * sizeof(int);
    size_t f16_off     = (start_bytes + 255) & ~(size_t)255;
    size_t f16_bytes   = (size_t)item_n * EMB * sizeof(__half);

    if (ws_size < f16_off + f16_bytes) {
        int ublocks = (n_users + 3) / 4;
        per_user_f32_kernel<<<ublocks, 256, 0, stream>>>(
            user_ids, group_ids, beh_item, beh_cnt, beh_user,
            user_table, item_table, out, n_users, n_beh);
        return;
    }

    int*    start    = (int*)d_ws;
    __half* item_f16 = (__half*)((char*)d_ws + f16_off);

    int n8 = (item_n * EMB) / 8;
    int prep_n = n8 > n_beh ? n8 : n_beh;
    prep_kernel<<<(prep_n + 255) / 256, 256, 0, stream>>>(
        item_table, item_f16, n8, beh_user, start, n_beh, n_users);

    int ublocks = (n_users + 3) / 4;
    per_user_kernel<<<ublocks, 256, 0, stream>>>(
        user_ids, group_ids, beh_item, beh_cnt,
        user_table, item_f16, start, out, n_users);
}